// Round 3
// baseline (708.915 us; speedup 1.0000x reference)
//
#include <hip/hip_runtime.h>
#include <math.h>

typedef unsigned int u32;
typedef unsigned long long u64;

#define BATCH 2
#define CH 128
#define NPTS 8192
#define KNB 16
#define GRP 8
#define EPSN 1e-5f

// ---- workspace layout (bytes), total ~10.8 MB ----
#define WS_A     0           // 8*128 f32   A' = s_g * (we_w1 @ pe_w2)
#define WS_PW1   4096        // 128 float4  folded pe_w1 + pe_bn (sx,sy,sz,bias)
#define WS_WE2   6144        // 64 f32      we_w2
#define WS_PTS   8192        // 16384 float4 {x,y,z,|p|^2}
#define WS_EQ    270336      // B*N*8 f32   t_g - s_g*eq
#define WS_EK    794624      // B*N*8 f32   s_g*ek
#define WS_IDX   1318912     // B*N*16 int
#define WS_VFT   2367488     // B*N*128 f32 v transposed (point-major)

__device__ __forceinline__ float d2f(float4 a, float4 b){
  #pragma clang fp contract(off)
  float dot = a.x*b.x + a.y*b.y + a.z*b.z;
  return (a.w + b.w) - 2.0f*dot;
}
__device__ __forceinline__ u64 shfl_xor_u64(u64 v, int m){
  int lo = __shfl_xor((int)(u32)v, m);
  int hi = __shfl_xor((int)(u32)(v >> 32), m);
  return (((u64)(u32)hi) << 32) | (u32)lo;
}

// ---------------- K0: tiny precompute ----------------
__global__ __launch_bounds__(256) void k0_precomp(
    const float* we_w1, const float* pe_w2, const float* pe_w1,
    const float* we_g, const float* we_v,
    const float* pe_g, const float* pe_b, const float* pe_m, const float* pe_v,
    const float* we_w2, float* wsA, float4* wsPW1, float* wsWE2){
  int t = threadIdx.x;
  for (int i = t; i < 1024; i += 256){
    int g = i >> 7, h = i & 127;
    float s = 0.f;
    for (int c = 0; c < 128; ++c) s = fmaf(we_w1[g*128+c], pe_w2[c*128+h], s);
    float sg = we_g[g] / sqrtf(we_v[g] + EPSN);
    wsA[i] = s * sg;
  }
  if (t < 128){
    float s = pe_g[t] / sqrtf(pe_v[t] + EPSN);
    float bb = pe_b[t] - pe_m[t] * s;
    wsPW1[t] = make_float4(s*pe_w1[t*3+0], s*pe_w1[t*3+1], s*pe_w1[t*3+2], bb);
  }
  if (t < 64) wsWE2[t] = we_w2[t];
}

// ---------------- K1: points + squared norms ----------------
__global__ __launch_bounds__(256) void k1_pts(const float* xyz, float4* pts){
  int id = blockIdx.x*256 + threadIdx.x;
  if (id >= BATCH*NPTS) return;
  int b = id >> 13, n = id & (NPTS-1);
  float x = xyz[(b*3+0)*NPTS + n];
  float y = xyz[(b*3+1)*NPTS + n];
  float z = xyz[(b*3+2)*NPTS + n];
  float sq;
  {
    #pragma clang fp contract(off)
    sq = (x*x + y*y) + z*z;
  }
  pts[id] = make_float4(x, y, z, sq);
}

// ---------------- K2: projections -> eqT, ekT, vfT ----------------
__global__ __launch_bounds__(256) void k2_proj(
    const float* x, const float* wq, const float* wk, const float* wv,
    const float* bnq_g, const float* bnq_b, const float* bnq_m, const float* bnq_v,
    const float* bnk_g, const float* bnk_b, const float* bnk_m, const float* bnk_v,
    const float* we_w1,
    const float* we_g, const float* we_b, const float* we_m, const float* we_v,
    float* eqT, float* ekT, float* vfT){
  __shared__ __align__(16) float qk[128][65];  // [channel][point]
  __shared__ float bnS[128], bnB[128];
  int t = threadIdx.x;
  int b = blockIdx.x >> 7;
  int n0 = (blockIdx.x & 127) * 64;
  int p = t & 63, og = t >> 6;
  const float* xp = x + (size_t)b*CH*NPTS + n0 + p;
  for (int mat = 0; mat < 3; ++mat){
    const float* W = (mat == 0) ? wq : ((mat == 1) ? wk : wv);
    if (mat < 2 && t < 128){
      const float* g_ = mat==0 ? bnq_g : bnk_g;
      const float* b_ = mat==0 ? bnq_b : bnk_b;
      const float* m_ = mat==0 ? bnq_m : bnk_m;
      const float* v_ = mat==0 ? bnq_v : bnk_v;
      float s = g_[t] / sqrtf(v_[t] + EPSN);
      bnS[t] = s;
      bnB[t] = b_[t] - m_[t] * s;
    }
    __syncthreads();   // also protects qk reuse across mats
    float acc[32];
    #pragma unroll
    for (int ii = 0; ii < 32; ++ii) acc[ii] = 0.f;
    for (int dd = 0; dd < 32; ++dd){
      float x0 = xp[(size_t)(4*dd+0)*NPTS];
      float x1 = xp[(size_t)(4*dd+1)*NPTS];
      float x2 = xp[(size_t)(4*dd+2)*NPTS];
      float x3 = xp[(size_t)(4*dd+3)*NPTS];
      #pragma unroll
      for (int ii = 0; ii < 32; ++ii){
        int o = og*32 + ii;
        float4 wu = *(const float4*)&W[o*128 + 4*dd];
        acc[ii] = fmaf(wu.x, x0, acc[ii]);
        acc[ii] = fmaf(wu.y, x1, acc[ii]);
        acc[ii] = fmaf(wu.z, x2, acc[ii]);
        acc[ii] = fmaf(wu.w, x3, acc[ii]);
      }
    }
    #pragma unroll
    for (int ii = 0; ii < 32; ++ii){
      int o = og*32 + ii;
      float v = acc[ii];
      if (mat < 2) v = fmaxf(fmaf(bnS[o], v, bnB[o]), 0.f);
      qk[o][p] = v;
    }
    __syncthreads();
    if (mat < 2){
      int g = t >> 5, pb = t & 31;
      float sg = we_g[g] / sqrtf(we_v[g] + EPSN);
      float tg = we_b[g] - we_m[g] * sg;
      #pragma unroll
      for (int half = 0; half < 2; ++half){
        int pp = pb + 32*half;
        float s = 0.f;
        for (int c = 0; c < 128; ++c) s = fmaf(we_w1[g*128+c], qk[c][pp], s);
        float val = (mat == 0) ? (tg - sg*s) : (sg*s);
        float* dst = (mat == 0) ? eqT : ekT;
        dst[(b*NPTS + n0 + pp)*8 + g] = val;
      }
    } else {
      for (int i = 0; i < 32; ++i){
        int f = t + 256*i;
        int c = f & 127, pp = f >> 7;
        vfT[((size_t)b*NPTS + n0 + pp)*CH + c] = qk[c][pp];
      }
    }
    __syncthreads();
  }
}

// ---------------- K3: exact KNN (threshold-collect + lexicographic select) ----------------
__global__ __launch_bounds__(256) void k3_knn(const float4* pts, int* idxout){
  __shared__ u64 buf[4][512];
  int t = threadIdx.x;
  int wv = t >> 6, lane = t & 63;
  int qid = blockIdx.x*4 + wv;
  int b = qid >> 13, n = qid & (NPTS-1);
  const float4* P = pts + b*NPTS;
  float4 pn = P[n];
  // pass 1: min positive d2 -> scale estimate
  float mn = 3.402823466e38f;
  for (int base = 0; base < NPTS; base += 64){
    float4 c = P[base + lane];
    float d2 = d2f(pn, c);
    if (d2 > 0.f) mn = fminf(mn, d2);
  }
  #pragma unroll
  for (int msk = 1; msk <= 32; msk <<= 1) mn = fminf(mn, __shfl_xor(mn, msk));
  float T = (mn < 3.0e38f) ? mn * 10.0f : 1.0f;
  if (!(T > 0.f)) T = 1e-12f;
  int cnt = 0;
  for (int att = 0; att < 60; ++att){
    cnt = 0;
    bool of = false;
    for (int base = 0; base < NPTS; base += 64){
      int m = base + lane;
      float4 c = P[m];
      float d2 = d2f(pn, c);
      bool pred = d2 < T;
      u64 mask = __ballot(pred);
      int cc = __popcll(mask);
      if (cnt + cc > 512){ of = true; break; }
      if (pred){
        u32 lo = (u32)(mask & 0xFFFFFFFFull), hi = (u32)(mask >> 32);
        int pos = cnt + (int)__builtin_amdgcn_mbcnt_hi(hi, __builtin_amdgcn_mbcnt_lo(lo, 0u));
        u32 db = __float_as_uint(d2);
        u32 key = (db & 0x80000000u) ? ~db : (db | 0x80000000u);  // monotone float->uint
        buf[wv][pos] = (((u64)key) << 32) | (u32)m;
      }
      cnt += cc;
    }
    if (!of && cnt >= 16) break;
    T = of ? T * 0.5f : T * 4.0f;
  }
  // extract 16 lexicographically-smallest (d2, idx)
  for (int r = 0; r < 16; ++r){
    __syncthreads();  // uniform: all waves run 16 rounds
    u64 lm = ~0ull; int ls = -1;
    for (int s = lane; s < cnt; s += 64){
      u64 v = buf[wv][s];
      if (v < lm){ lm = v; ls = s; }
    }
    u64 gm = lm;
    #pragma unroll
    for (int msk = 1; msk <= 32; msk <<= 1){
      u64 o = shfl_xor_u64(gm, msk);
      gm = (o < gm) ? o : gm;
    }
    if (lm == gm && ls >= 0) buf[wv][ls] = ~0ull;
    if (lane == 0){
      int sel = (gm == ~0ull) ? n : (int)(gm & 0xFFFFFFFFull);
      idxout[qid*16 + r] = sel;
    }
  }
}

// ---------------- K4: fused attention + output projection ----------------
#define HSTR 140
#define H2STR 136
__global__ __launch_bounds__(256) void k4_attn(
    const float4* pts, const float* eqT, const float* ekT, const int* idxw,
    const float* vfT, const float* wsA, const float4* wsPW1, const float* wsWE2,
    const float* pe_w2, const float* wo,
    const float* bno_g, const float* bno_b, const float* bno_m, const float* bno_v,
    float* out){
  __shared__ __align__(16) float smHid[4][16*HSTR];
  __shared__ __align__(16) float smH[4][8*H2STR];
  __shared__ float smw[4][16*8];
  __shared__ __align__(16) float4 smW1[128];
  __shared__ __align__(16) float smOutv[8][128];
  int t = threadIdx.x;
  int wv = t >> 6, lane = t & 63;
  int b = blockIdx.x >> 10;
  int n0 = (blockIdx.x & 1023) * 8;
  if (t < 128) smW1[t] = wsPW1[t];
  __syncthreads();
  int k = lane >> 2, q = lane & 3;
  for (int r = 0; r < 2; ++r){
    int pl = r*4 + wv;
    int n = n0 + pl;
    int gq = b*NPTS + n;
    float4 pn = pts[gq];
    float4 eqa = *(const float4*)&eqT[gq*8];
    float4 eqb = *(const float4*)&eqT[gq*8+4];
    int j = idxw[gq*16 + k];
    int gj = b*NPTS + j;
    float4 pj = pts[gj];
    float4 eka = *(const float4*)&ekT[gj*8];
    float4 ekb = *(const float4*)&ekT[gj*8+4];
    float rx = pj.x - pn.x, ry = pj.y - pn.y, rz = pj.z - pn.z;
    // ee: the (ek' + eq') affine term — added ONCE, after the q-lane reduction
    float ee[8] = {eka.x+eqa.x, eka.y+eqa.y, eka.z+eqa.z, eka.w+eqa.w,
                   ekb.x+eqb.x, ekb.y+eqb.y, ekb.z+eqb.z, ekb.w+eqb.w};
    float lp[8] = {0.f, 0.f, 0.f, 0.f, 0.f, 0.f, 0.f, 0.f};
    #pragma unroll
    for (int i = 0; i < 8; ++i){
      int hb = 4*q + 16*i;
      float hv0, hv1, hv2, hv3;
      {
        float4 w1;
        w1 = smW1[hb+0]; hv0 = fmaxf(fmaf(w1.x, rx, fmaf(w1.y, ry, fmaf(w1.z, rz, w1.w))), 0.f);
        w1 = smW1[hb+1]; hv1 = fmaxf(fmaf(w1.x, rx, fmaf(w1.y, ry, fmaf(w1.z, rz, w1.w))), 0.f);
        w1 = smW1[hb+2]; hv2 = fmaxf(fmaf(w1.x, rx, fmaf(w1.y, ry, fmaf(w1.z, rz, w1.w))), 0.f);
        w1 = smW1[hb+3]; hv3 = fmaxf(fmaf(w1.x, rx, fmaf(w1.y, ry, fmaf(w1.z, rz, w1.w))), 0.f);
      }
      *(float4*)&smHid[wv][k*HSTR + hb] = make_float4(hv0, hv1, hv2, hv3);
      #pragma unroll
      for (int g = 0; g < 8; ++g){
        float4 a4 = *(const float4*)&wsA[g*128 + hb];
        lp[g] = fmaf(a4.x, hv0, lp[g]);
        lp[g] = fmaf(a4.y, hv1, lp[g]);
        lp[g] = fmaf(a4.z, hv2, lp[g]);
        lp[g] = fmaf(a4.w, hv3, lp[g]);
      }
    }
    #pragma unroll
    for (int g = 0; g < 8; ++g){
      lp[g] += __shfl_xor(lp[g], 1);
      lp[g] += __shfl_xor(lp[g], 2);
      lp[g] = fmaxf(lp[g] + ee[g], 0.f);   // relu(bn(we_w1@rel)); ee added once
    }
    float lo0 = 0.f, lo1 = 0.f;
    #pragma unroll
    for (int g = 0; g < 8; ++g){
      lo0 = fmaf(wsWE2[(2*q+0)*8 + g], lp[g], lo0);
      lo1 = fmaf(wsWE2[(2*q+1)*8 + g], lp[g], lo1);
    }
    float m0 = lo0, m1 = lo1;
    #pragma unroll
    for (int msk = 4; msk <= 32; msk <<= 1){
      m0 = fmaxf(m0, __shfl_xor(m0, msk));
      m1 = fmaxf(m1, __shfl_xor(m1, msk));
    }
    float e0 = __expf(lo0 - m0), e1 = __expf(lo1 - m1);
    float s0 = e0, s1 = e1;
    #pragma unroll
    for (int msk = 4; msk <= 32; msk <<= 1){
      s0 += __shfl_xor(s0, msk);
      s1 += __shfl_xor(s1, msk);
    }
    float w0 = e0 / s0, w1 = e1 / s1;
    *(float2*)&smw[wv][k*8 + 2*q] = make_float2(w0, w1);
    __syncthreads();
    // H[g][h] = sum_k w[g,k] * hid[k][h]
    {
      int g3 = lane >> 3, hh = lane & 7;
      float wk16[16];
      #pragma unroll
      for (int kk = 0; kk < 16; ++kk) wk16[kk] = smw[wv][kk*8 + g3];
      #pragma unroll
      for (int ii = 0; ii < 4; ++ii){
        int hb = 4*hh + 32*ii;
        float ax = 0.f, ay = 0.f, az = 0.f, aw = 0.f;
        #pragma unroll
        for (int kk = 0; kk < 16; ++kk){
          float4 h4 = *(const float4*)&smHid[wv][kk*HSTR + hb];
          ax = fmaf(wk16[kk], h4.x, ax);
          ay = fmaf(wk16[kk], h4.y, ay);
          az = fmaf(wk16[kk], h4.z, az);
          aw = fmaf(wk16[kk], h4.w, aw);
        }
        *(float4*)&smH[wv][g3*H2STR + hb] = make_float4(ax, ay, az, aw);
      }
    }
    __syncthreads();
    // outv[c] = pe_w2[c,:]@H[g(c)] + sum_k w[g,k]*v[j_k][c]
    {
      int jj16[16];
      #pragma unroll
      for (int kk = 0; kk < 16; ++kk) jj16[kk] = idxw[gq*16 + kk];
      #pragma unroll
      for (int half = 0; half < 2; ++half){
        int c = lane + 64*half;
        int g = c >> 4;
        float acc = 0.f;
        for (int i = 0; i < 32; ++i){
          float4 pw = *(const float4*)&pe_w2[c*128 + 4*i];
          float4 h4 = *(const float4*)&smH[wv][g*H2STR + 4*i];
          acc = fmaf(pw.x, h4.x, acc);
          acc = fmaf(pw.y, h4.y, acc);
          acc = fmaf(pw.z, h4.z, acc);
          acc = fmaf(pw.w, h4.w, acc);
        }
        #pragma unroll
        for (int kk = 0; kk < 16; ++kk){
          float wgk = smw[wv][kk*8 + g];
          acc = fmaf(wgk, vfT[((size_t)b*NPTS + jj16[kk])*CH + c], acc);
        }
        smOutv[pl][c] = acc;
      }
    }
    __syncthreads();
  }
  // phase B: final projection wo + bno, f32 store
  {
    int o = t & 127, ph = t >> 7;
    float so = bno_g[o] / sqrtf(bno_v[o] + EPSN);
    float bo = bno_b[o] - bno_m[o] * so;
    float fa[4] = {0.f, 0.f, 0.f, 0.f};
    for (int i = 0; i < 32; ++i){
      float4 pw = *(const float4*)&wo[o*128 + 4*i];
      #pragma unroll
      for (int p4 = 0; p4 < 4; ++p4){
        float4 h4 = *(const float4*)&smOutv[ph*4 + p4][4*i];
        fa[p4] = fmaf(pw.x, h4.x, fa[p4]);
        fa[p4] = fmaf(pw.y, h4.y, fa[p4]);
        fa[p4] = fmaf(pw.z, h4.z, fa[p4]);
        fa[p4] = fmaf(pw.w, h4.w, fa[p4]);
      }
    }
    float4 st;
    st.x = fmaf(so, fa[0], bo);
    st.y = fmaf(so, fa[1], bo);
    st.z = fmaf(so, fa[2], bo);
    st.w = fmaf(so, fa[3], bo);
    *(float4*)&out[((size_t)b*CH + o)*NPTS + n0 + ph*4] = st;
  }
}

extern "C" void kernel_launch(void* const* d_in, const int* in_sizes, int n_in,
                              void* d_out, int out_size, void* d_ws, size_t ws_size,
                              hipStream_t stream){
  const float* x     = (const float*)d_in[0];
  const float* xyz   = (const float*)d_in[1];
  const float* wq    = (const float*)d_in[2];
  const float* bnq_g = (const float*)d_in[3];
  const float* bnq_b = (const float*)d_in[4];
  const float* bnq_m = (const float*)d_in[5];
  const float* bnq_v = (const float*)d_in[6];
  const float* wk    = (const float*)d_in[7];
  const float* bnk_g = (const float*)d_in[8];
  const float* bnk_b = (const float*)d_in[9];
  const float* bnk_m = (const float*)d_in[10];
  const float* bnk_v = (const float*)d_in[11];
  const float* wv    = (const float*)d_in[12];
  const float* pe_w1 = (const float*)d_in[13];
  const float* pe_g  = (const float*)d_in[14];
  const float* pe_b  = (const float*)d_in[15];
  const float* pe_m  = (const float*)d_in[16];
  const float* pe_v  = (const float*)d_in[17];
  const float* pe_w2 = (const float*)d_in[18];
  const float* we_w1 = (const float*)d_in[19];
  const float* we_g  = (const float*)d_in[20];
  const float* we_b  = (const float*)d_in[21];
  const float* we_m  = (const float*)d_in[22];
  const float* we_v  = (const float*)d_in[23];
  const float* we_w2 = (const float*)d_in[24];
  const float* wo    = (const float*)d_in[25];
  const float* bno_g = (const float*)d_in[26];
  const float* bno_b = (const float*)d_in[27];
  const float* bno_m = (const float*)d_in[28];
  const float* bno_v = (const float*)d_in[29];

  char* ws = (char*)d_ws;
  float*  wsA   = (float*)(ws + WS_A);
  float4* wsPW1 = (float4*)(ws + WS_PW1);
  float*  wsWE2 = (float*)(ws + WS_WE2);
  float4* pts   = (float4*)(ws + WS_PTS);
  float*  eqT   = (float*)(ws + WS_EQ);
  float*  ekT   = (float*)(ws + WS_EK);
  int*    idxw  = (int*)(ws + WS_IDX);
  float*  vfT   = (float*)(ws + WS_VFT);
  float*  outp  = (float*)d_out;

  k0_precomp<<<dim3(1), dim3(256), 0, stream>>>(we_w1, pe_w2, pe_w1, we_g, we_v,
                                                pe_g, pe_b, pe_m, pe_v, we_w2,
                                                wsA, wsPW1, wsWE2);
  k1_pts<<<dim3(64), dim3(256), 0, stream>>>(xyz, pts);
  k2_proj<<<dim3(256), dim3(256), 0, stream>>>(x, wq, wk, wv,
                                               bnq_g, bnq_b, bnq_m, bnq_v,
                                               bnk_g, bnk_b, bnk_m, bnk_v,
                                               we_w1, we_g, we_b, we_m, we_v,
                                               eqT, ekT, vfT);
  k3_knn<<<dim3(4096), dim3(256), 0, stream>>>(pts, idxw);
  k4_attn<<<dim3(2048), dim3(256), 0, stream>>>(pts, eqT, ekT, idxw, vfT,
                                                wsA, wsPW1, wsWE2, pe_w2, wo,
                                                bno_g, bno_b, bno_m, bno_v, outp);
}